// Round 1
// baseline (749.586 us; speedup 1.0000x reference)
//
#include <hip/hip_runtime.h>
#include <math.h>

#define Bsz 32
#define Lsz 4096
#define Hsz 1024

// Kernel A: v[b,h] = sum_g hid[b,g] * W[g,h]
// grid (H/256, B), 256 threads. hid[b,g] is block-uniform -> scalar loads.
__global__ __launch_bounds__(256) void proj_hidden_k(const float* __restrict__ hid,
                                                     const float* __restrict__ W,
                                                     float* __restrict__ v) {
    const int h = blockIdx.x * 256 + threadIdx.x;
    const int b = blockIdx.y;
    const float* hb = hid + b * Hsz;
    float acc = 0.f;
#pragma unroll 8
    for (int g = 0; g < Hsz; ++g) {
        acc += hb[g] * W[g * Hsz + h];
    }
    v[b * Hsz + h] = acc;
}

// Kernel B: energies[b,l] = dot(enc[l,b,:], v[b,:])
// One wave per 32 consecutive l (same b). v[b] cached in 16 VGPRs/lane.
// enc row (l,b,:) is 4KB contiguous: 4 x float4 per lane.
__global__ __launch_bounds__(256) void energies_k(const float* __restrict__ enc,
                                                  const float* __restrict__ v,
                                                  float* __restrict__ energy) {
    const int lane = threadIdx.x & 63;
    const int wid  = blockIdx.x * 4 + (threadIdx.x >> 6);  // 0..4095
    const int b  = wid >> 7;            // 128 waves per batch row
    const int l0 = (wid & 127) * 32;    // 32 rows per wave

    const float4* v4 = (const float4*)(v + b * Hsz);
    float4 vf[4];
#pragma unroll
    for (int k = 0; k < 4; ++k) vf[k] = v4[k * 64 + lane];

    float res = 0.f;
#pragma unroll 4
    for (int r = 0; r < 32; ++r) {
        const int l = l0 + r;
        const float4* row = (const float4*)(enc + ((size_t)l * Bsz + b) * Hsz);
        float p = 0.f;
#pragma unroll
        for (int k = 0; k < 4; ++k) {
            float4 e = row[k * 64 + lane];
            p += e.x * vf[k].x + e.y * vf[k].y + e.z * vf[k].z + e.w * vf[k].w;
        }
#pragma unroll
        for (int off = 32; off > 0; off >>= 1)
            p += __shfl_xor(p, off, 64);
        if (lane == r) res = p;   // lane r keeps row r's result
    }
    if (lane < 32) energy[b * Lsz + l0 + lane] = res;  // coalesced 128B store
}

// Kernel C: softmax over L per batch row. One block (256 thr) per b.
__global__ __launch_bounds__(256) void softmax_k(const float* __restrict__ energy,
                                                 float* __restrict__ out) {
    __shared__ float smax[4], ssum[4];
    const int b = blockIdx.x;
    const int tid = threadIdx.x;
    const int lane = tid & 63, w = tid >> 6;
    const float4* row = (const float4*)(energy + b * Lsz);  // 1024 float4
    float4 e[4];
#pragma unroll
    for (int k = 0; k < 4; ++k) e[k] = row[k * 256 + tid];

    float m = -INFINITY;
#pragma unroll
    for (int k = 0; k < 4; ++k)
        m = fmaxf(m, fmaxf(fmaxf(e[k].x, e[k].y), fmaxf(e[k].z, e[k].w)));
#pragma unroll
    for (int off = 32; off > 0; off >>= 1) m = fmaxf(m, __shfl_xor(m, off, 64));
    if (lane == 0) smax[w] = m;
    __syncthreads();
    m = fmaxf(fmaxf(smax[0], smax[1]), fmaxf(smax[2], smax[3]));

    float s = 0.f;
#pragma unroll
    for (int k = 0; k < 4; ++k) {
        e[k].x = __expf(e[k].x - m); e[k].y = __expf(e[k].y - m);
        e[k].z = __expf(e[k].z - m); e[k].w = __expf(e[k].w - m);
        s += e[k].x + e[k].y + e[k].z + e[k].w;
    }
#pragma unroll
    for (int off = 32; off > 0; off >>= 1) s += __shfl_xor(s, off, 64);
    if (lane == 0) ssum[w] = s;
    __syncthreads();
    s = ssum[0] + ssum[1] + ssum[2] + ssum[3];
    const float inv = 1.f / s;

    float4* o = (float4*)(out + b * Lsz);
#pragma unroll
    for (int k = 0; k < 4; ++k) {
        float4 r = e[k];
        r.x *= inv; r.y *= inv; r.z *= inv; r.w *= inv;
        o[k * 256 + tid] = r;
    }
}

extern "C" void kernel_launch(void* const* d_in, const int* in_sizes, int n_in,
                              void* d_out, int out_size, void* d_ws, size_t ws_size,
                              hipStream_t stream) {
    const float* hid = (const float*)d_in[0];   // (1,B,H)
    const float* enc = (const float*)d_in[1];   // (L,B,H)
    const float* W   = (const float*)d_in[2];   // (H,H)
    // d_in[3] = bias: energies[b,l] += dot(hid[b], bias) is constant over l,
    // softmax is shift-invariant -> dropped (bias is zeros in harness anyway).
    float* out = (float*)d_out;                 // (B,1,L)

    float* v      = (float*)d_ws;               // B*H floats   = 128 KiB
    float* energy = v + Bsz * Hsz;              // B*L floats   = 512 KiB

    proj_hidden_k<<<dim3(Hsz / 256, Bsz), 256, 0, stream>>>(hid, W, v);
    energies_k<<<dim3((Lsz * Bsz) / (4 * 32)), 256, 0, stream>>>(enc, v, energy);
    softmax_k<<<dim3(Bsz), 256, 0, stream>>>(energy, out);
}

// Round 2
// 721.882 us; speedup vs baseline: 1.0384x; 1.0384x over previous
//
#include <hip/hip_runtime.h>
#include <math.h>

#define Bsz 32
#define Lsz 4096
#define Hsz 1024

// Kernel A: v[b,h] = sum_g hid[b,g] * W[g,h]
// grid (H/64, B), 256 threads: 4 g-chunks of 256 per h, LDS reduce.
// 512 blocks -> 2 blocks/CU, 8 waves/CU (vs 1 wave/SIMD before).
__global__ __launch_bounds__(256) void proj_hidden_k(const float* __restrict__ hid,
                                                     const float* __restrict__ W,
                                                     float* __restrict__ v) {
    __shared__ float red[256];
    const int hl    = threadIdx.x & 63;
    const int chunk = threadIdx.x >> 6;
    const int h = blockIdx.x * 64 + hl;
    const int b = blockIdx.y;
    const float* hb = hid + b * Hsz + chunk * 256;       // wave-uniform scalar loads
    const float* Wp = W + (size_t)(chunk * 256) * Hsz + h;
    float acc = 0.f;
#pragma unroll 8
    for (int g = 0; g < 256; ++g)
        acc += hb[g] * Wp[(size_t)g * Hsz];
    red[threadIdx.x] = acc;
    __syncthreads();
    if (chunk == 0)
        v[b * Hsz + h] = red[hl] + red[hl + 64] + red[hl + 128] + red[hl + 192];
}

// Kernel B: energies[b,l] = dot(enc[l,b,:], v[b,:])
// One wave per 32 consecutive l (same b). Per-lane partials accumulated in
// vals[32] (no shuffles in hot loop); one 32-value butterfly reduce at end.
__global__ __launch_bounds__(256) void energies_k(const float* __restrict__ enc,
                                                  const float* __restrict__ v,
                                                  float* __restrict__ energy) {
    const int lane = threadIdx.x & 63;
    const int wid  = blockIdx.x * 4 + (threadIdx.x >> 6);  // 0..4095
    const int b  = wid >> 7;            // 128 waves per batch row
    const int l0 = (wid & 127) * 32;    // 32 rows per wave

    const float4* v4 = (const float4*)(v + b * Hsz);
    float4 vf[4];
#pragma unroll
    for (int k = 0; k < 4; ++k) vf[k] = v4[k * 64 + lane];

    float vals[32];
#pragma unroll 4
    for (int r = 0; r < 32; ++r) {
        const float4* row = (const float4*)(enc + ((size_t)(l0 + r) * Bsz + b) * Hsz);
        float p = 0.f;
#pragma unroll
        for (int k = 0; k < 4; ++k) {
            float4 e = row[k * 64 + lane];
            p += e.x * vf[k].x + e.y * vf[k].y + e.z * vf[k].z + e.w * vf[k].w;
        }
        vals[r] = p;
    }

    // Butterfly exchange-reduce: 5 steps within 32-lane halves, then xor-32.
    // After step p (mask 2^p), lane bit p selects row bit (4-p).
    int cnt = 32;
#pragma unroll
    for (int p = 0; p < 5; ++p) {
        const int m = 1 << p;
        const int half = cnt >> 1;
        const bool hi = (lane & m) != 0;
#pragma unroll
        for (int j = 0; j < half; ++j) {
            float send = hi ? vals[j] : vals[half + j];
            float recv = __shfl_xor(send, m, 64);
            vals[j] = (hi ? vals[half + j] : vals[j]) + recv;
        }
        cnt = half;
    }
    float tot = vals[0] + __shfl_xor(vals[0], 32, 64);

    if (lane < 32) {
        // lane -> row is bitreverse5
        const int row = ((lane & 1) << 4) | ((lane & 2) << 2) | (lane & 4) |
                        ((lane & 8) >> 2) | ((lane & 16) >> 4);
        energy[b * Lsz + l0 + row] = tot;
    }
}

// Kernel C: softmax over L per batch row. One block (256 thr) per b.
__global__ __launch_bounds__(256) void softmax_k(const float* __restrict__ energy,
                                                 float* __restrict__ out) {
    __shared__ float smax[4], ssum[4];
    const int b = blockIdx.x;
    const int tid = threadIdx.x;
    const int lane = tid & 63, w = tid >> 6;
    const float4* row = (const float4*)(energy + b * Lsz);  // 1024 float4
    float4 e[4];
#pragma unroll
    for (int k = 0; k < 4; ++k) e[k] = row[k * 256 + tid];

    float m = -INFINITY;
#pragma unroll
    for (int k = 0; k < 4; ++k)
        m = fmaxf(m, fmaxf(fmaxf(e[k].x, e[k].y), fmaxf(e[k].z, e[k].w)));
#pragma unroll
    for (int off = 32; off > 0; off >>= 1) m = fmaxf(m, __shfl_xor(m, off, 64));
    if (lane == 0) smax[w] = m;
    __syncthreads();
    m = fmaxf(fmaxf(smax[0], smax[1]), fmaxf(smax[2], smax[3]));

    float s = 0.f;
#pragma unroll
    for (int k = 0; k < 4; ++k) {
        e[k].x = __expf(e[k].x - m); e[k].y = __expf(e[k].y - m);
        e[k].z = __expf(e[k].z - m); e[k].w = __expf(e[k].w - m);
        s += e[k].x + e[k].y + e[k].z + e[k].w;
    }
#pragma unroll
    for (int off = 32; off > 0; off >>= 1) s += __shfl_xor(s, off, 64);
    if (lane == 0) ssum[w] = s;
    __syncthreads();
    s = ssum[0] + ssum[1] + ssum[2] + ssum[3];
    const float inv = 1.f / s;

    float4* o = (float4*)(out + b * Lsz);
#pragma unroll
    for (int k = 0; k < 4; ++k) {
        float4 r = e[k];
        r.x *= inv; r.y *= inv; r.z *= inv; r.w *= inv;
        o[k * 256 + tid] = r;
    }
}

extern "C" void kernel_launch(void* const* d_in, const int* in_sizes, int n_in,
                              void* d_out, int out_size, void* d_ws, size_t ws_size,
                              hipStream_t stream) {
    const float* hid = (const float*)d_in[0];   // (1,B,H)
    const float* enc = (const float*)d_in[1];   // (L,B,H)
    const float* W   = (const float*)d_in[2];   // (H,H)
    // d_in[3] = bias: contributes dot(hid[b], bias), constant over l ->
    // softmax shift-invariant -> dropped (bias is zeros anyway).
    float* out = (float*)d_out;                 // (B,1,L)

    float* v      = (float*)d_ws;               // B*H floats   = 128 KiB
    float* energy = v + Bsz * Hsz;              // B*L floats   = 512 KiB

    proj_hidden_k<<<dim3(Hsz / 64, Bsz), 256, 0, stream>>>(hid, W, v);
    energies_k<<<dim3((Lsz * Bsz) / (4 * 32)), 256, 0, stream>>>(enc, v, energy);
    softmax_k<<<dim3(Bsz), 256, 0, stream>>>(energy, out);
}